// Round 4
// baseline (317.982 us; speedup 1.0000x reference)
//
#include <hip/hip_runtime.h>

// SpecAugment: B=64, C=2, F=128, T=2048, fp32.
// out[b,c,f,t] = apply[b] ? (keep[b,f,t] ? spec : 0) + noise*0.01 : spec
//
// V4 (resubmit — round 3 was an infra failure, no counters returned):
// persistent-block streaming (Guideline 11 shape for memory-bound ops).
//  - 2048 blocks (8/CU) x 256 threads. Each block owns a CONTIGUOUS 64 KB
//    range (4096 float4) = 1/32 of one batch -> batch index, apply flag and
//    all mask params are resolved ONCE per block, not per 4 KB micro-block
//    (V1 re-derived them 32768 times and churned blocks at 73% occupancy).
//  - 16-chunk loop, register prefetch of chunk c+1 issued before the store
//    of chunk c: a rolling 1-deep software pipeline the compiler preserves
//    (loop-carried dep), unlike the flat load batches of V2/V3 which the
//    backend re-serialized (VGPR counts proved it).
//  - Non-applied blocks: pure copy loop, no noise traffic, near-zero VALU.
//  - Per chunk: freq mask is block-uniform scalar; time mask has only 2
//    per-thread variants (chunk parity), precomputed before the loop.

#define BB 64
#define CC 2
#define FF 128
#define TT 2048
#define VB (CC * FF * (TT / 4))   // 131072 float4 per batch
#define NBLK 2048                 // 8 blocks per CU
#define FPB 4096                  // float4 per block (64 KB)
#define CPB 16                    // chunks per block (256 float4 each)

typedef float f32x4 __attribute__((ext_vector_type(4)));

__global__ __launch_bounds__(256) void specaug_kernel(
    const float* __restrict__ spec,
    const float* __restrict__ apply_u,
    const float* __restrict__ f_width_u,
    const float* __restrict__ f_start_u,
    const float* __restrict__ t_width_u,
    const float* __restrict__ t_start_u,
    const float* __restrict__ noise,
    float* __restrict__ out)
{
    const int bx  = blockIdx.x;
    const int b   = bx >> 5;                 // 32 blocks per batch
    const int tid = threadIdx.x;
    const int base = bx * FPB + tid;         // float4 index, max < 2^23

    const f32x4* __restrict__ sp = (const f32x4*)spec;
    const f32x4* __restrict__ np = (const f32x4*)noise;
    f32x4* __restrict__ op = (f32x4*)out;

    // Block-uniform apply branch.
    if (apply_u[b] > 0.5f) {
        // Pure copy: 16 chunks, 1-chunk register prefetch.
        f32x4 pre = sp[base];
        #pragma unroll 2
        for (int c = 0; c < CPB; ++c) {
            const f32x4 cur = pre;
            if (c + 1 < CPB) pre = sp[base + (c + 1) * 256];
            op[base + c * 256] = cur;
        }
        return;
    }

    // ---- applied path: params once per block ----
    // (identical math to reference; freq range needs no clamp: F-w >= 109;
    //  time range clamped to >= 1)
    int fs[2], fw[2], ts[2], tw[2];
    #pragma unroll
    for (int k = 0; k < 2; ++k) {
        fw[k] = (int)floorf(f_width_u[b * 2 + k] * 20.0f);
        fs[k] = (int)floorf(f_start_u[b * 2 + k] * (float)(FF - fw[k]));
        tw[k] = (int)floorf(t_width_u[b * 2 + k] * 40.0f);
        ts[k] = (int)floorf(t_start_u[b * 2 + k] *
                            fmaxf((float)(TT - tw[k]), 1.0f));
    }

    // Time masks: chunk c touches tv = tid (c even) or tid+256 (c odd).
    bool tm[2][4];
    #pragma unroll
    for (int h = 0; h < 2; ++h) {
        const int t0 = (tid + h * 256) << 2;
        #pragma unroll
        for (int jj = 0; jj < 4; ++jj) {
            const int t = t0 + jj;
            tm[h][jj] = ((t >= ts[0]) & (t < ts[0] + tw[0])) |
                        ((t >= ts[1]) & (t < ts[1] + tw[1]));
        }
    }

    // Main loop: prefetch chunk c+1, compute+store chunk c.
    f32x4 spre = sp[base];
    f32x4 npre = np[base];
    #pragma unroll 2
    for (int c = 0; c < CPB; ++c) {
        const f32x4 scur = spre;
        const f32x4 ncur = npre;
        if (c + 1 < CPB) {
            spre = sp[base + (c + 1) * 256];
            npre = np[base + (c + 1) * 256];
        }
        // Freq mask: block-uniform per chunk. Row-in-batch advances by 8
        // per block and by 1 per chunk pair: f = ((bx&15)*8 + c/2) & 127.
        const int f = ((bx << 3) + (c >> 1)) & (FF - 1);
        const bool fm = ((f >= fs[0]) & (f < fs[0] + fw[0])) |
                        ((f >= fs[1]) & (f < fs[1] + fw[1]));
        const bool* tmj = tm[c & 1];
        f32x4 o;
        #pragma unroll
        for (int jj = 0; jj < 4; ++jj) {
            const bool keep = !(fm | tmj[jj]);
            o[jj] = (keep ? scur[jj] : 0.0f) + ncur[jj] * 0.01f;
        }
        op[base + c * 256] = o;
    }
}

extern "C" void kernel_launch(void* const* d_in, const int* in_sizes, int n_in,
                              void* d_out, int out_size, void* d_ws, size_t ws_size,
                              hipStream_t stream) {
    const float* spec      = (const float*)d_in[0];
    const float* apply_u   = (const float*)d_in[1];
    const float* f_width_u = (const float*)d_in[2];
    const float* f_start_u = (const float*)d_in[3];
    const float* t_width_u = (const float*)d_in[4];
    const float* t_start_u = (const float*)d_in[5];
    const float* noise     = (const float*)d_in[6];
    float* out             = (float*)d_out;

    specaug_kernel<<<NBLK, 256, 0, stream>>>(
        spec, apply_u, f_width_u, f_start_u, t_width_u, t_start_u, noise, out);
}

// Round 5
// 303.224 us; speedup vs baseline: 1.0487x; 1.0487x over previous
//
#include <hip/hip_runtime.h>

// SpecAugment: B=64, C=2, F=128, T=2048, fp32.
// out[b,c,f,t] = apply[b] ? (keep[b,f,t] ? spec : 0) + noise*0.01 : spec
//
// V5 = V1 (best measured structure: 1 float4/thread, 32768 one-shot blocks,
// 91.5 us) with EXACTLY ONE change: non-temporal stores.
// Theory: inputs (spec+noise = 256 MB) ~= the 256 MiB Infinity Cache; the
// 128 MB write-allocate stream evicts half the inputs each iteration
// (FETCH_SIZE showed 107.5 MB HBM reads vs 192 MB vector reads). nt stores
// keep the write stream out of the LLC so inputs stay resident -> reads
// become LLC hits, HBM carries mostly the write stream.
// (V2 also had nt stores but confounded them with a 256KB-strided layout
// that independently regressed ~10% — this is the clean A/B vs V1.)

#define BB 64
#define CC 2
#define FF 128
#define TT 2048

typedef float f32x4 __attribute__((ext_vector_type(4)));

__global__ __launch_bounds__(256) void specaug_kernel(
    const float* __restrict__ spec,
    const float* __restrict__ apply_u,
    const float* __restrict__ f_width_u,
    const float* __restrict__ f_start_u,
    const float* __restrict__ t_width_u,
    const float* __restrict__ t_start_u,
    const float* __restrict__ noise,
    float* __restrict__ out)
{
    // One float4 along T per thread. T/4 = 512 vecs per (b,c,f) row.
    const int vec = blockIdx.x * blockDim.x + threadIdx.x;
    const int tv  = vec & (TT / 4 - 1);      // 0..511
    const int row = vec >> 9;                // (b*C + c)*F + f
    const int f   = row & (FF - 1);
    const int b   = row >> 8;                // row / (C*F) with C=2, F=128
    const int t0  = tv << 2;

    const f32x4 s = ((const f32x4*)spec)[vec];
    f32x4 o;

    // b is wave-uniform (each wave spans 256 consecutive t within one row),
    // so this branch does not diverge and non-applied batches skip the
    // noise load entirely.
    if (apply_u[b] <= 0.5f) {
        // Frequency masks (no clamp on range; F - w >= 109 > 0 always).
        bool fmask = false;
        #pragma unroll
        for (int k = 0; k < 2; ++k) {
            const int   w   = (int)floorf(f_width_u[b * 2 + k] * 20.0f);
            const float rng = (float)(FF - w);
            const int   s0  = (int)floorf(f_start_u[b * 2 + k] * rng);
            fmask |= (f >= s0) & (f < s0 + w);
        }
        // Time masks (range clamped to >= 1).
        int ts0[2], tw[2];
        #pragma unroll
        for (int k = 0; k < 2; ++k) {
            const int   w   = (int)floorf(t_width_u[b * 2 + k] * 40.0f);
            const float rng = fmaxf((float)(TT - w), 1.0f);
            ts0[k] = (int)floorf(t_start_u[b * 2 + k] * rng);
            tw[k]  = w;
        }

        const f32x4 n = ((const f32x4*)noise)[vec];
        f32x4 ov;
        #pragma unroll
        for (int j = 0; j < 4; ++j) {
            const int t = t0 + j;
            bool tmask = false;
            #pragma unroll
            for (int k = 0; k < 2; ++k)
                tmask |= (t >= ts0[k]) & (t < ts0[k] + tw[k]);
            const bool keep = (!fmask) & (!tmask);
            ov[j] = (keep ? s[j] : 0.0f) + n[j] * 0.01f;
        }
        o = ov;
    } else {
        o = s;
    }
    __builtin_nontemporal_store(o, &((f32x4*)out)[vec]);
}

extern "C" void kernel_launch(void* const* d_in, const int* in_sizes, int n_in,
                              void* d_out, int out_size, void* d_ws, size_t ws_size,
                              hipStream_t stream) {
    const float* spec      = (const float*)d_in[0];
    const float* apply_u   = (const float*)d_in[1];
    const float* f_width_u = (const float*)d_in[2];
    const float* f_start_u = (const float*)d_in[3];
    const float* t_width_u = (const float*)d_in[4];
    const float* t_start_u = (const float*)d_in[5];
    const float* noise     = (const float*)d_in[6];
    float* out             = (float*)d_out;

    const int total_vecs = BB * CC * FF * (TT / 4);   // 8,388,608
    const int block = 256;
    const int grid  = total_vecs / block;             // 32,768

    specaug_kernel<<<grid, block, 0, stream>>>(
        spec, apply_u, f_width_u, f_start_u, t_width_u, t_start_u, noise, out);
}

// Round 6
// 299.269 us; speedup vs baseline: 1.0625x; 1.0132x over previous
//
#include <hip/hip_runtime.h>

// SpecAugment: B=64, C=2, F=128, T=2048, fp32.
// out[b,c,f,t] = apply[b] ? (keep[b,f,t] ? spec : 0) + noise*0.01 : spec
//
// V6 = V1 exactly (best measured: 91.5 us/dispatch, 2.67 TB/s HBM).
// Session summary of failed alternatives (all >= V1):
//   V2 8 vec/thread @256KB stride  111.4 us  (flat MLP batch re-serialized)
//   V3 4 vec/thread + asm fence    100.9 us  (compiler still sank loads)
//   V4 persistent 8 blk/CU pipeline 107.5 us (static partition -> imbalance)
//   V5 V1 + nontemporal stores      98.0 us  (FETCH unchanged -> no
//      write-allocate traffic existed; nt just lost write buffering)
// Traffic is at floor (noise skipped for non-applied batches); five
// structures converge at ~2.5-2.7 TB/s HBM for this 2-read+1-write mix.

#define BB 64
#define CC 2
#define FF 128
#define TT 2048

typedef float f32x4 __attribute__((ext_vector_type(4)));

__global__ __launch_bounds__(256) void specaug_kernel(
    const float* __restrict__ spec,
    const float* __restrict__ apply_u,
    const float* __restrict__ f_width_u,
    const float* __restrict__ f_start_u,
    const float* __restrict__ t_width_u,
    const float* __restrict__ t_start_u,
    const float* __restrict__ noise,
    float* __restrict__ out)
{
    // One float4 along T per thread. T/4 = 512 vecs per (b,c,f) row.
    const int vec = blockIdx.x * blockDim.x + threadIdx.x;
    const int tv  = vec & (TT / 4 - 1);      // 0..511
    const int row = vec >> 9;                // (b*C + c)*F + f
    const int f   = row & (FF - 1);
    const int b   = row >> 8;                // row / (C*F) with C=2, F=128
    const int t0  = tv << 2;

    const f32x4 s = ((const f32x4*)spec)[vec];
    f32x4 o;

    // b is wave-uniform (each wave spans 256 consecutive t within one row),
    // so this branch does not diverge and non-applied batches skip the
    // noise load entirely.
    if (apply_u[b] <= 0.5f) {
        // Frequency masks (no clamp on range; F - w >= 109 > 0 always).
        bool fmask = false;
        #pragma unroll
        for (int k = 0; k < 2; ++k) {
            const int   w   = (int)floorf(f_width_u[b * 2 + k] * 20.0f);
            const float rng = (float)(FF - w);
            const int   s0  = (int)floorf(f_start_u[b * 2 + k] * rng);
            fmask |= (f >= s0) & (f < s0 + w);
        }
        // Time masks (range clamped to >= 1).
        int ts0[2], tw[2];
        #pragma unroll
        for (int k = 0; k < 2; ++k) {
            const int   w   = (int)floorf(t_width_u[b * 2 + k] * 40.0f);
            const float rng = fmaxf((float)(TT - w), 1.0f);
            ts0[k] = (int)floorf(t_start_u[b * 2 + k] * rng);
            tw[k]  = w;
        }

        const f32x4 n = ((const f32x4*)noise)[vec];
        f32x4 ov;
        #pragma unroll
        for (int j = 0; j < 4; ++j) {
            const int t = t0 + j;
            bool tmask = false;
            #pragma unroll
            for (int k = 0; k < 2; ++k)
                tmask |= (t >= ts0[k]) & (t < ts0[k] + tw[k]);
            const bool keep = (!fmask) & (!tmask);
            ov[j] = (keep ? s[j] : 0.0f) + n[j] * 0.01f;
        }
        o = ov;
    } else {
        o = s;
    }
    ((f32x4*)out)[vec] = o;
}

extern "C" void kernel_launch(void* const* d_in, const int* in_sizes, int n_in,
                              void* d_out, int out_size, void* d_ws, size_t ws_size,
                              hipStream_t stream) {
    const float* spec      = (const float*)d_in[0];
    const float* apply_u   = (const float*)d_in[1];
    const float* f_width_u = (const float*)d_in[2];
    const float* f_start_u = (const float*)d_in[3];
    const float* t_width_u = (const float*)d_in[4];
    const float* t_start_u = (const float*)d_in[5];
    const float* noise     = (const float*)d_in[6];
    float* out             = (float*)d_out;

    const int total_vecs = BB * CC * FF * (TT / 4);   // 8,388,608
    const int block = 256;
    const int grid  = total_vecs / block;             // 32,768

    specaug_kernel<<<grid, block, 0, stream>>>(
        spec, apply_u, f_width_u, f_start_u, t_width_u, t_start_u, noise, out);
}